// Round 12
// baseline (172.256 us; speedup 1.0000x reference)
//
#include <hip/hip_runtime.h>
#include <hip/hip_bf16.h>

// Problem constants
constexpr int BB  = 2;
constexpr int CHN = 256;
constexpr int HH  = 80;
constexpr int WW  = 80;
constexpr int EE  = 64;
constexpr int HO  = 160;
constexpr int WO  = 160;

// Workspace layout (float offsets)
constexpr int OFF_WT_EN = 0;                    // [256][64]  w1_en transposed
constexpr int OFF_WT_DE = 16384;                // [256][64]  w1_de transposed
constexpr int OFF_WC    = 32768;                // [64][3][3][25] conv2_k transposed
constexpr int OFF_CES   = 47168;                // [B][4][162][162][16] padded+scrambled ce
constexpr int CES_SZ    = 2 * 4 * 162 * 162 * 16;   // 3,359,232
constexpr int OFF_CDG   = OFF_CES + CES_SZ;     // [B][82][82][64] padded cd
constexpr int CDG_SZ    = 2 * 82 * 82 * 64;     // 860,672
constexpr int OFF_GATE  = OFF_CDG + CDG_SZ;     // [B][80][80]
constexpr int OFF_KERN  = OFF_GATE + 2 * 80 * 80;   // [B][80][80][25][4] softmaxed (o-major, q-minor!)

constexpr int NPB = BB * 82 * 82;     // 13448

// X-macro: apply F to 0..24 (forces compile-time indices -> registers; rule #20)
#define REP25(F) F(0) F(1) F(2) F(3) F(4) F(5) F(6) F(7) F(8) F(9) F(10) F(11) \
                 F(12) F(13) F(14) F(15) F(16) F(17) F(18) F(19) F(20) F(21) F(22) F(23) F(24)

// ---------------------------------------------------------------------------
// Prep: transpose weights so inner-loop weight reads are wave-uniform (s_load)
// ---------------------------------------------------------------------------
__global__ __launch_bounds__(256) void fade_prep(
    const float* __restrict__ w1_en, const float* __restrict__ w1_de,
    const float* __restrict__ conv2_k, float* __restrict__ ws) {
  int idx = blockIdx.x * 256 + threadIdx.x;
  if (idx < 16384) {
    int c = idx >> 6, e = idx & 63;           // dest = [c][e]
    ws[OFF_WT_EN + idx] = w1_en[e * CHN + c];
    ws[OFF_WT_DE + idx] = w1_de[e * CHN + c];
  }
  if (idx < 14400) {
    // dest idx = (e*9 + t)*25 + o ; src = conv2_k[(o*64 + e)*9 + t]
    int e = idx / 225, rem = idx % 225, t = rem / 25, o = rem % 25;
    ws[OFF_WC + idx] = conv2_k[(o * EE + e) * 9 + t];
  }
}

// ---------------------------------------------------------------------------
// border: zero-fill the pad border of ce_s (yy=0,161; xx=0,161).
// 82,432 float4 units total.
// ---------------------------------------------------------------------------
__global__ __launch_bounds__(256) void fade_border(float* __restrict__ ces) {
  int idx = blockIdx.x * 256 + threadIdx.x;
  if (idx >= 82432) return;
  int e4 = idx & 3;
  int rest = idx >> 2;
  int posb = rest % 644;
  int rest2 = rest / 644;
  int q = rest2 & 3, b = rest2 >> 2;
  int yy, xx;
  if (posb < 162)      { yy = 0;   xx = posb; }
  else if (posb < 324) { yy = 161; xx = posb - 162; }
  else if (posb < 484) { xx = 0;   yy = posb - 324 + 1; }
  else                 { xx = 161; yy = posb - 484 + 1; }
  float4 z = make_float4(0.f, 0.f, 0.f, 0.f);
  *(float4*)(ces + ((((size_t)b * 4 + q) * 162 + yy) * 162 + xx) * 16 + e4 * 4) = z;
}

// ---------------------------------------------------------------------------
// conv1a: ce = 1x1(en) -> scrambled ce_s interior, LDS-STAGED.
// Block = 512 thr = 64 consecutive x (lane) x 8 e-group waves.
// Grid = B x 160 rows x 3 tiles (x0 = 0,64,96; overlap writes identical).
// ---------------------------------------------------------------------------
__global__ __launch_bounds__(512) void fade_conv1a(
    const float* __restrict__ en, const float* __restrict__ b1_en,
    const float* __restrict__ wt_en, float* __restrict__ ces) {
  __shared__ float buf[128][64];
  int bi = blockIdx.x;
  int b = bi / 480, r = bi % 480;
  int y = r / 3, t = r % 3;
  int x0 = (t < 2) ? t * 64 : 96;
  int tid = threadIdx.x;
  int lane = tid & 63;
  int eg = __builtin_amdgcn_readfirstlane(tid >> 6);   // 0..7
  int x = x0 + lane;

  const float* ep = en + ((size_t)b * CHN * HO + y) * WO + x;   // + c*HO*WO

  float acc[8];
#pragma unroll
  for (int e = 0; e < 8; ++e) acc[e] = b1_en[eg * 8 + e];

#pragma unroll
  for (int p = 0; p < 2; ++p) {
    __syncthreads();
    // stage 128 channels: wave eg loads channels {i*8+eg}
#pragma unroll
    for (int i = 0; i < 16; ++i) {
      int cl = i * 8 + eg;
      buf[cl][lane] = ep[(size_t)(p * 128 + cl) * HO * WO];
    }
    __syncthreads();
    // compute: 128 channels x 8 outputs
    for (int c0 = 0; c0 < 128; c0 += 8) {
      float v[8];
#pragma unroll
      for (int j = 0; j < 8; ++j) v[j] = buf[c0 + j][lane];
#pragma unroll
      for (int j = 0; j < 8; ++j) {
        const float* wr = wt_en + (p * 128 + c0 + j) * 64 + eg * 8;
#pragma unroll
        for (int e = 0; e < 8; ++e) acc[e] = fmaf(v[j], wr[e], acc[e]);
      }
    }
  }

  // scrambled write: e = 8eg+l -> q = l&3, e' = 2eg + (l>>2)
  int yy = y + 1, xx = x + 1;
  float* outp = ces + ((((size_t)b * 4) * 162 + yy) * 162 + xx) * 16;
  constexpr size_t QSTR = (size_t)162 * 162 * 16;
#pragma unroll
  for (int q = 0; q < 4; ++q) {
    float2 v = make_float2(acc[q], acc[4 + q]);
    *(float2*)(outp + (size_t)q * QSTR + eg * 2) = v;
  }
}

// ---------------------------------------------------------------------------
// conv1b: cd = 1x1(de) -> padded cdg, + gate. Exact r7 part-B shape
// (256 thr, 4 e-groups x acc[16]) -- measured healthy at r7.
// ---------------------------------------------------------------------------
__global__ __launch_bounds__(256) void fade_conv1b(
    const float* __restrict__ de,
    const float* __restrict__ gate_w, const float* __restrict__ gate_b,
    const float* __restrict__ wt_de,
    float* __restrict__ cdg, float* __restrict__ gateo) {
  int tid = threadIdx.x;
  int id64 = tid & 63;
  int eg = __builtin_amdgcn_readfirstlane(tid >> 6);   // 0..3
  int pos = blockIdx.x * 64 + id64;
  if (pos >= NPB) return;

  int b = pos / (82 * 82), r = pos % (82 * 82);
  int yy = r / 82, xx = r % 82;
  int y = yy - 1, x = xx - 1;
  float* cop = cdg + (((size_t)b * 82 + yy) * 82 + xx) * 64 + eg * 16;
  if (y >= 0 && y < HH && x >= 0 && x < WW) {
    float acc[16];
#pragma unroll
    for (int e = 0; e < 16; ++e) acc[e] = 0.f;
    float g = gate_b[0];
    const float* dp = de + (size_t)b * CHN * HH * WW + (size_t)y * WW + x;
    float cur[8];
#pragma unroll
    for (int j = 0; j < 8; ++j) cur[j] = dp[(size_t)j * HH * WW];
    for (int c0 = 0; c0 < CHN; c0 += 8) {
      float nxt[8];
      if (c0 + 8 < CHN) {
#pragma unroll
        for (int j = 0; j < 8; ++j) nxt[j] = dp[(size_t)(c0 + 8 + j) * HH * WW];
      }
#pragma unroll
      for (int j = 0; j < 8; ++j) {
        float v = cur[j];
        const float* wr = wt_de + (c0 + j) * 64 + eg * 16;
#pragma unroll
        for (int e = 0; e < 16; ++e) acc[e] = fmaf(v, wr[e], acc[e]);
        g = fmaf(v, gate_w[c0 + j], g);
      }
      if (c0 + 8 < CHN) {
#pragma unroll
        for (int j = 0; j < 8; ++j) cur[j] = nxt[j];
      }
    }
#pragma unroll
    for (int m = 0; m < 4; ++m) {
      float4 v = make_float4(acc[4 * m], acc[4 * m + 1], acc[4 * m + 2], acc[4 * m + 3]);
      *(float4*)(cop + m * 4) = v;
    }
    if (eg == 0)
      gateo[((size_t)b * 80 + y) * 80 + x] = 1.f / (1.f + __expf(-g));
  } else {
    float4 z = make_float4(0.f, 0.f, 0.f, 0.f);
#pragma unroll
    for (int m = 0; m < 4; ++m) *(float4*)(cop + m * 4) = z;
  }
}

// ---------------------------------------------------------------------------
// kern: r7 compute structure (runtime d-loop is load-bearing -- r8 lesson)
// but LDS halved via TWO-PHASE reduction: part[64][101] (25.9KB); waves 0-3
// WRITE partials, sync, waves 4-7 ADD into the same slots, sync, reduce 4.
// LDS 58.4KB -> 32KB exactly => 4 blocks/CU (was 2): r11 profile showed
// Occupancy 27% / VALUBusy 40% -- latency-exposed at 2 blocks/CU.
// ---------------------------------------------------------------------------
__global__ __launch_bounds__(512) void fade_kern(
    const float* __restrict__ WC, const float* __restrict__ CES,
    const float* __restrict__ CDG, const float* __restrict__ conv2_b,
    float* __restrict__ KERN) {
  __shared__ float part[64 * 101];   // [row][(wv&3)*25+o], stride 101 (conflict-free)
  __shared__ float score[64 * 27];
  int bi = blockIdx.x;
  int b = bi / 400, t = bi % 400;
  int th0 = (t / 20) * 4, tw0 = (t % 20) * 4;
  int tid = threadIdx.x;
  int lane = tid & 63;
  int wv = __builtin_amdgcn_readfirstlane(tid >> 6);   // 0..7 K-slice
  int cell = lane >> 2, q = lane & 3;
  int h = th0 + (cell >> 2), w = tw0 + (cell & 3);

#define KDECL_(i) float a##i = 0.f;
  REP25(KDECL_)

  // one channel's 25-FMA block; weight base is wave-uniform -> s_load
#define KCH(val, base) { const float vv = (val); const float* wb = (base); \
    REP25(KFMA_) }
#define KFMA_(i) a##i = fmaf(vv, wb[(i)], a##i);

  // --- k_de slice: channels e in [8wv, 8wv+8) ---
  for (int d = 0; d < 9; ++d) {
    int di = d / 3, dj = d - 3 * di;
    const float* cp = CDG + (((size_t)b * 82 + (h + di)) * 82 + (w + dj)) * 64 + 8 * wv;
    float4 v0 = *(const float4*)(cp);
    float4 v1 = *(const float4*)(cp + 4);
    const float* wt = WC + (8 * wv * 9 + d) * 25;   // + k*225 per channel
    KCH(v0.x, wt)        KCH(v0.y, wt + 225)  KCH(v0.z, wt + 450)  KCH(v0.w, wt + 675)
    KCH(v1.x, wt + 900)  KCH(v1.y, wt + 1125) KCH(v1.z, wt + 1350) KCH(v1.w, wt + 1575)
  }

  // --- k_en slice: channels i in [8wv, 8wv+8); pad-group g = wv>>1 ---
  {
    int g = wv >> 1;
    const int pt = (g < 2) ? 1 : 0;
    const int pl = (g & 1) ? 0 : 1;
    const int eb = 8 * (wv & 1);
    for (int d = 0; d < 9; ++d) {
      int di = d / 3, dj = d - 3 * di;
      int yy = 2 * h + di - pt + 1;
      int xx = 2 * w + dj - pl + 1;
      const float* cp = CES + ((((size_t)b * 4 + q) * 162 + yy) * 162 + xx) * 16 + eb;
      float4 v0 = *(const float4*)(cp);
      float4 v1 = *(const float4*)(cp + 4);
      const float* wt = WC + (8 * wv * 9 + d) * 25;
      KCH(v0.x, wt)        KCH(v0.y, wt + 225)  KCH(v0.z, wt + 450)  KCH(v0.w, wt + 675)
      KCH(v1.x, wt + 900)  KCH(v1.y, wt + 1125) KCH(v1.z, wt + 1350) KCH(v1.w, wt + 1575)
    }
  }

  // two-phase partial reduction into part[row][ (wv&3)*25 + o ]
  {
    int pbase = lane * 101 + (wv & 3) * 25;
    if (wv < 4) {
#define KST_(i) part[pbase + (i)] = a##i;
      REP25(KST_)
    }
    __syncthreads();
    if (wv >= 4) {
#define KAD_(i) part[pbase + (i)] += a##i;
      REP25(KAD_)
    }
  }
  __syncthreads();

  // reduce 4 partials per (row, o); thread (row = tid&63, sub = tid>>6)
  {
    int row = tid & 63, sub = tid >> 6;
    int nO = (sub == 7) ? 4 : 3;
    for (int m = 0; m < nO; ++m) {
      int o = sub * 3 + m;
      float s = 0.f;
#pragma unroll
      for (int w4 = 0; w4 < 4; ++w4) s += part[row * 101 + w4 * 25 + o];
      score[row * 27 + o] = s + 2.f * conv2_b[o];   // bias in BOTH k_en and k_de
    }
  }
  __syncthreads();

  // softmax + write: wave 0, one row per lane. KERN layout: [site][o][q].
  if (tid < 64) {
    int sbase = tid * 27;
#define SLD_(i) float s##i = score[sbase + (i)];
    REP25(SLD_)
    float mx = s0;
#define SMX_(i) mx = fmaxf(mx, s##i);
    REP25(SMX_)
    float sum = 0.f;
#define SEX_(i) s##i = __expf(s##i - mx); sum += s##i;
    REP25(SEX_)
    float inv = 1.f / sum;
    int cl = tid >> 2, qq = tid & 3;
    int hh = th0 + (cl >> 2), ww2 = tw0 + (cl & 3);
    float* kp = KERN + (size_t)(b * 6400 + hh * 80 + ww2) * 100;
#define SWR_(i) kp[(i) * 4 + qq] = s##i * inv;
    REP25(SWR_)
  }
}

// ---------------------------------------------------------------------------
// final: CARAFE + gate blend. Grid = B x 200 tiles x 8 channel-chunks.
// Block = 256 threads = 32 cells (8w x 4h) x 8 sub-groups of 4 channels.
// KERN is [site][o][q] -> 25 named float4 regs (q = .x/.y/.z/.w = (s1 s2)).
// ---------------------------------------------------------------------------
__global__ __launch_bounds__(256) void fade_final(
    const float* __restrict__ en, const float* __restrict__ de,
    const float* __restrict__ KERN, const float* __restrict__ GATE,
    float* __restrict__ out) {
  __shared__ float sde[32 * 105];   // 32 channels x (8 rows x 13 cols pad)
  int bi = blockIdx.x;
  int b = bi / 1600, r = bi % 1600;
  int t = r >> 3, cc = r & 7;
  int th0 = (t / 10) * 4, tw0 = (t % 10) * 8;
  int tid = threadIdx.x;
  int sg = tid >> 5, cell = tid & 31;
  int chh = cell >> 3, cw = cell & 7;
  int h = th0 + chh, w = tw0 + cw;

  // stage de: channels cc*32 .. +32, rows th0-2..+5, cols tw0-2..+9
  for (int kk = tid; kk < 3072; kk += 256) {
    int ci = kk / 96, rem = kk % 96, rr = rem / 12, c2 = rem % 12;
    int dr = th0 - 2 + rr, dc = tw0 - 2 + c2;
    float v = 0.f;
    if (dr >= 0 && dr < HH && dc >= 0 && dc < WW)
      v = de[((size_t)(b * CHN + cc * 32 + ci) * HH + dr) * WW + dc];
    sde[ci * 105 + rr * 13 + c2] = v;
  }
  __syncthreads();

  const float4* kp4 = (const float4*)(KERN + (size_t)(b * 6400 + h * 80 + w) * 100);
#define FKD_(i) float4 k##i = kp4[(i)];
  REP25(FKD_)
  float gv = GATE[((size_t)b * 80 + h) * 80 + w];
  float gv1 = 1.f - gv;

#pragma unroll
  for (int j = 0; j < 4; ++j) {
    int c = cc * 32 + sg * 4 + j;
    int sbase2 = (sg * 4 + j) * 105 + chh * 13 + cw;
#define FWD_(i) float w##i = sde[sbase2 + ((i) / 5) * 13 + ((i) % 5)];
    REP25(FWD_)
    float s00 = 0.f, s01 = 0.f, s10 = 0.f, s11 = 0.f;
#define FCF_(i) s00 = fmaf(w##i, k##i.x, s00); s01 = fmaf(w##i, k##i.y, s01); \
                s10 = fmaf(w##i, k##i.z, s10); s11 = fmaf(w##i, k##i.w, s11);
    REP25(FCF_)

    const float* ep = en + ((size_t)(b * CHN + c) * HO + 2 * h) * WO + 2 * w;
    float* op = out + ((size_t)(b * CHN + c) * HO + 2 * h) * WO + 2 * w;
    float2 e0 = *(const float2*)(ep);
    float2 e1 = *(const float2*)(ep + WO);
    float2 r0, r1;
    r0.x = fmaf(gv, e0.x, gv1 * s00);
    r0.y = fmaf(gv, e0.y, gv1 * s01);
    r1.x = fmaf(gv, e1.x, gv1 * s10);
    r1.y = fmaf(gv, e1.y, gv1 * s11);
    *(float2*)(op) = r0;
    *(float2*)(op + WO) = r1;
  }
}

// ---------------------------------------------------------------------------
extern "C" void kernel_launch(void* const* d_in, const int* in_sizes, int n_in,
                              void* d_out, int out_size, void* d_ws, size_t ws_size,
                              hipStream_t stream) {
  const float* en      = (const float*)d_in[0];
  const float* de      = (const float*)d_in[1];
  const float* gate_w  = (const float*)d_in[2];
  const float* gate_b  = (const float*)d_in[3];
  const float* w1_en   = (const float*)d_in[4];
  const float* b1_en   = (const float*)d_in[5];
  const float* w1_de   = (const float*)d_in[6];
  const float* conv2_k = (const float*)d_in[7];
  const float* conv2_b = (const float*)d_in[8];
  float* ws  = (float*)d_ws;
  float* out = (float*)d_out;

  float* wt_en = ws + OFF_WT_EN;
  float* wt_de = ws + OFF_WT_DE;
  float* wc    = ws + OFF_WC;
  float* cesb  = ws + OFF_CES;
  float* cdgb  = ws + OFF_CDG;
  float* gateo = ws + OFF_GATE;
  float* kernb = ws + OFF_KERN;

  hipLaunchKernelGGL(fade_prep,   dim3(64),   dim3(256), 0, stream, w1_en, w1_de, conv2_k, ws);
  hipLaunchKernelGGL(fade_border, dim3(322),  dim3(256), 0, stream, cesb);
  hipLaunchKernelGGL(fade_conv1a, dim3(960),  dim3(512), 0, stream, en, b1_en, wt_en, cesb);
  hipLaunchKernelGGL(fade_conv1b, dim3(211),  dim3(256), 0, stream,
                     de, gate_w, gate_b, wt_de, cdgb, gateo);
  hipLaunchKernelGGL(fade_kern,   dim3(800),  dim3(512), 0, stream,
                     wc, cesb, cdgb, conv2_b, kernb);
  hipLaunchKernelGGL(fade_final,  dim3(3200), dim3(256), 0, stream,
                     en, de, kernb, gateo, out);
}

// Round 13
// 160.137 us; speedup vs baseline: 1.0757x; 1.0757x over previous
//
#include <hip/hip_runtime.h>
#include <hip/hip_bf16.h>

// Problem constants
constexpr int BB  = 2;
constexpr int CHN = 256;
constexpr int HH  = 80;
constexpr int WW  = 80;
constexpr int EE  = 64;
constexpr int HO  = 160;
constexpr int WO  = 160;

// Workspace layout (float offsets)
constexpr int OFF_WT_EN = 0;                    // [256][64]  w1_en transposed
constexpr int OFF_WT_DE = 16384;                // [256][64]  w1_de transposed
constexpr int OFF_WC    = 32768;                // [64][3][3][25] conv2_k transposed
constexpr int OFF_CES   = 47168;                // [B][4][162][162][16] padded+scrambled ce
constexpr int CES_SZ    = 2 * 4 * 162 * 162 * 16;   // 3,359,232
constexpr int OFF_CDG   = OFF_CES + CES_SZ;     // [B][82][82][64] padded cd
constexpr int CDG_SZ    = 2 * 82 * 82 * 64;     // 860,672
constexpr int OFF_GATE  = OFF_CDG + CDG_SZ;     // [B][80][80]
constexpr int OFF_KERN  = OFF_GATE + 2 * 80 * 80;   // [B][80][80][25][4] softmaxed (o-major, q-minor!)

constexpr int NPB = BB * 82 * 82;     // 13448

// X-macro: apply F to 0..24 (forces compile-time indices -> registers; rule #20)
#define REP25(F) F(0) F(1) F(2) F(3) F(4) F(5) F(6) F(7) F(8) F(9) F(10) F(11) \
                 F(12) F(13) F(14) F(15) F(16) F(17) F(18) F(19) F(20) F(21) F(22) F(23) F(24)

// ---------------------------------------------------------------------------
// Prep: transpose weights so inner-loop weight reads are wave-uniform (s_load)
// ---------------------------------------------------------------------------
__global__ __launch_bounds__(256) void fade_prep(
    const float* __restrict__ w1_en, const float* __restrict__ w1_de,
    const float* __restrict__ conv2_k, float* __restrict__ ws) {
  int idx = blockIdx.x * 256 + threadIdx.x;
  if (idx < 16384) {
    int c = idx >> 6, e = idx & 63;           // dest = [c][e]
    ws[OFF_WT_EN + idx] = w1_en[e * CHN + c];
    ws[OFF_WT_DE + idx] = w1_de[e * CHN + c];
  }
  if (idx < 14400) {
    // dest idx = (e*9 + t)*25 + o ; src = conv2_k[(o*64 + e)*9 + t]
    int e = idx / 225, rem = idx % 225, t = rem / 25, o = rem % 25;
    ws[OFF_WC + idx] = conv2_k[(o * EE + e) * 9 + t];
  }
}

// ---------------------------------------------------------------------------
// border: zero-fill the pad border of ce_s (yy=0,161; xx=0,161).
// 82,432 float4 units total.
// ---------------------------------------------------------------------------
__global__ __launch_bounds__(256) void fade_border(float* __restrict__ ces) {
  int idx = blockIdx.x * 256 + threadIdx.x;
  if (idx >= 82432) return;
  int e4 = idx & 3;
  int rest = idx >> 2;
  int posb = rest % 644;
  int rest2 = rest / 644;
  int q = rest2 & 3, b = rest2 >> 2;
  int yy, xx;
  if (posb < 162)      { yy = 0;   xx = posb; }
  else if (posb < 324) { yy = 161; xx = posb - 162; }
  else if (posb < 484) { xx = 0;   yy = posb - 324 + 1; }
  else                 { xx = 161; yy = posb - 484 + 1; }
  float4 z = make_float4(0.f, 0.f, 0.f, 0.f);
  *(float4*)(ces + ((((size_t)b * 4 + q) * 162 + yy) * 162 + xx) * 16 + e4 * 4) = z;
}

// ---------------------------------------------------------------------------
// conv1a: ce = 1x1(en) -> scrambled ce_s interior, LDS-STAGED.
// Block = 512 thr = 64 consecutive x (lane) x 8 e-group waves.
// Grid = B x 160 rows x 3 tiles (x0 = 0,64,96; overlap writes identical).
// ---------------------------------------------------------------------------
__global__ __launch_bounds__(512) void fade_conv1a(
    const float* __restrict__ en, const float* __restrict__ b1_en,
    const float* __restrict__ wt_en, float* __restrict__ ces) {
  __shared__ float buf[128][64];
  int bi = blockIdx.x;
  int b = bi / 480, r = bi % 480;
  int y = r / 3, t = r % 3;
  int x0 = (t < 2) ? t * 64 : 96;
  int tid = threadIdx.x;
  int lane = tid & 63;
  int eg = __builtin_amdgcn_readfirstlane(tid >> 6);   // 0..7
  int x = x0 + lane;

  const float* ep = en + ((size_t)b * CHN * HO + y) * WO + x;   // + c*HO*WO

  float acc[8];
#pragma unroll
  for (int e = 0; e < 8; ++e) acc[e] = b1_en[eg * 8 + e];

#pragma unroll
  for (int p = 0; p < 2; ++p) {
    __syncthreads();
    // stage 128 channels: wave eg loads channels {i*8+eg}
#pragma unroll
    for (int i = 0; i < 16; ++i) {
      int cl = i * 8 + eg;
      buf[cl][lane] = ep[(size_t)(p * 128 + cl) * HO * WO];
    }
    __syncthreads();
    // compute: 128 channels x 8 outputs
    for (int c0 = 0; c0 < 128; c0 += 8) {
      float v[8];
#pragma unroll
      for (int j = 0; j < 8; ++j) v[j] = buf[c0 + j][lane];
#pragma unroll
      for (int j = 0; j < 8; ++j) {
        const float* wr = wt_en + (p * 128 + c0 + j) * 64 + eg * 8;
#pragma unroll
        for (int e = 0; e < 8; ++e) acc[e] = fmaf(v[j], wr[e], acc[e]);
      }
    }
  }

  // scrambled write: e = 8eg+l -> q = l&3, e' = 2eg + (l>>2)
  int yy = y + 1, xx = x + 1;
  float* outp = ces + ((((size_t)b * 4) * 162 + yy) * 162 + xx) * 16;
  constexpr size_t QSTR = (size_t)162 * 162 * 16;
#pragma unroll
  for (int q = 0; q < 4; ++q) {
    float2 v = make_float2(acc[q], acc[4 + q]);
    *(float2*)(outp + (size_t)q * QSTR + eg * 2) = v;
  }
}

// ---------------------------------------------------------------------------
// conv1b: cd = 1x1(de) -> padded cdg, + gate. Exact r7 part-B shape
// (256 thr, 4 e-groups x acc[16]) -- measured healthy at r7.
// ---------------------------------------------------------------------------
__global__ __launch_bounds__(256) void fade_conv1b(
    const float* __restrict__ de,
    const float* __restrict__ gate_w, const float* __restrict__ gate_b,
    const float* __restrict__ wt_de,
    float* __restrict__ cdg, float* __restrict__ gateo) {
  int tid = threadIdx.x;
  int id64 = tid & 63;
  int eg = __builtin_amdgcn_readfirstlane(tid >> 6);   // 0..3
  int pos = blockIdx.x * 64 + id64;
  if (pos >= NPB) return;

  int b = pos / (82 * 82), r = pos % (82 * 82);
  int yy = r / 82, xx = r % 82;
  int y = yy - 1, x = xx - 1;
  float* cop = cdg + (((size_t)b * 82 + yy) * 82 + xx) * 64 + eg * 16;
  if (y >= 0 && y < HH && x >= 0 && x < WW) {
    float acc[16];
#pragma unroll
    for (int e = 0; e < 16; ++e) acc[e] = 0.f;
    float g = gate_b[0];
    const float* dp = de + (size_t)b * CHN * HH * WW + (size_t)y * WW + x;
    float cur[8];
#pragma unroll
    for (int j = 0; j < 8; ++j) cur[j] = dp[(size_t)j * HH * WW];
    for (int c0 = 0; c0 < CHN; c0 += 8) {
      float nxt[8];
      if (c0 + 8 < CHN) {
#pragma unroll
        for (int j = 0; j < 8; ++j) nxt[j] = dp[(size_t)(c0 + 8 + j) * HH * WW];
      }
#pragma unroll
      for (int j = 0; j < 8; ++j) {
        float v = cur[j];
        const float* wr = wt_de + (c0 + j) * 64 + eg * 16;
#pragma unroll
        for (int e = 0; e < 16; ++e) acc[e] = fmaf(v, wr[e], acc[e]);
        g = fmaf(v, gate_w[c0 + j], g);
      }
      if (c0 + 8 < CHN) {
#pragma unroll
        for (int j = 0; j < 8; ++j) cur[j] = nxt[j];
      }
    }
#pragma unroll
    for (int m = 0; m < 4; ++m) {
      float4 v = make_float4(acc[4 * m], acc[4 * m + 1], acc[4 * m + 2], acc[4 * m + 3]);
      *(float4*)(cop + m * 4) = v;
    }
    if (eg == 0)
      gateo[((size_t)b * 80 + y) * 80 + x] = 1.f / (1.f + __expf(-g));
  } else {
    float4 z = make_float4(0.f, 0.f, 0.f, 0.f);
#pragma unroll
    for (int m = 0; m < 4; ++m) *(float4*)(cop + m * 4) = z;
  }
}

// ---------------------------------------------------------------------------
// kern: MERGED k_de+k_en tap loop. r12 profile (occ 37%, VALU 41%, dur ~same
// as r11 despite 2x blocks/CU) proved the stall is the s_load weight stream,
// not wave latency. k_de and k_en use IDENTICAL weight blocks and sum into
// the same score, so  sum(w*a_de) + sum(w*a_en) = sum(w*(a_de+a_en)):
// sum activations first -> HALF the FMAs and HALF the weight traffic.
// Runtime d-loop retained (r8 lesson: keeps live-set small, no spill).
// Two-phase LDS reduction retained (32KB -> 4 blocks/CU).
// ---------------------------------------------------------------------------
__global__ __launch_bounds__(512) void fade_kern(
    const float* __restrict__ WC, const float* __restrict__ CES,
    const float* __restrict__ CDG, const float* __restrict__ conv2_b,
    float* __restrict__ KERN) {
  __shared__ float part[64 * 101];   // [row][(wv&3)*25+o], stride 101 (conflict-free)
  __shared__ float score[64 * 27];
  int bi = blockIdx.x;
  int b = bi / 400, t = bi % 400;
  int th0 = (t / 20) * 4, tw0 = (t % 20) * 4;
  int tid = threadIdx.x;
  int lane = tid & 63;
  int wv = __builtin_amdgcn_readfirstlane(tid >> 6);   // 0..7 K-slice
  int cell = lane >> 2, q = lane & 3;
  int h = th0 + (cell >> 2), w = tw0 + (cell & 3);

#define KDECL_(i) float a##i = 0.f;
  REP25(KDECL_)

  // one channel's 25-FMA block; weight base is wave-uniform -> s_load
#define KCH(val, base) { const float vv = (val); const float* wb = (base); \
    REP25(KFMA_) }
#define KFMA_(i) a##i = fmaf(vv, wb[(i)], a##i);

  // --- merged k_de + k_en over 9 taps; channels 8wv..8wv+8 ---
  // k_en channel i = 16*(wv>>1) + 8*(wv&1) + k = 8wv + k  == k_de channel ✓
  {
    int g = wv >> 1;
    const int pt = (g < 2) ? 1 : 0;
    const int pl = (g & 1) ? 0 : 1;
    const int eb = 8 * (wv & 1);
    for (int d = 0; d < 9; ++d) {
      int di = d / 3, dj = d - 3 * di;
      const float* cpd = CDG + (((size_t)b * 82 + (h + di)) * 82 + (w + dj)) * 64 + 8 * wv;
      float4 u0 = *(const float4*)(cpd);
      float4 u1 = *(const float4*)(cpd + 4);
      int yy = 2 * h + di - pt + 1;
      int xx = 2 * w + dj - pl + 1;
      const float* cpe = CES + ((((size_t)b * 4 + q) * 162 + yy) * 162 + xx) * 16 + eb;
      float4 v0 = *(const float4*)(cpe);
      float4 v1 = *(const float4*)(cpe + 4);
      const float* wt = WC + (8 * wv * 9 + d) * 25;   // + k*225 per channel
      KCH(u0.x + v0.x, wt)         KCH(u0.y + v0.y, wt + 225)
      KCH(u0.z + v0.z, wt + 450)   KCH(u0.w + v0.w, wt + 675)
      KCH(u1.x + v1.x, wt + 900)   KCH(u1.y + v1.y, wt + 1125)
      KCH(u1.z + v1.z, wt + 1350)  KCH(u1.w + v1.w, wt + 1575)
    }
  }

  // two-phase partial reduction into part[row][ (wv&3)*25 + o ]
  {
    int pbase = lane * 101 + (wv & 3) * 25;
    if (wv < 4) {
#define KST_(i) part[pbase + (i)] = a##i;
      REP25(KST_)
    }
    __syncthreads();
    if (wv >= 4) {
#define KAD_(i) part[pbase + (i)] += a##i;
      REP25(KAD_)
    }
  }
  __syncthreads();

  // reduce 4 partials per (row, o); thread (row = tid&63, sub = tid>>6)
  {
    int row = tid & 63, sub = tid >> 6;
    int nO = (sub == 7) ? 4 : 3;
    for (int m = 0; m < nO; ++m) {
      int o = sub * 3 + m;
      float s = 0.f;
#pragma unroll
      for (int w4 = 0; w4 < 4; ++w4) s += part[row * 101 + w4 * 25 + o];
      score[row * 27 + o] = s + 2.f * conv2_b[o];   // bias in BOTH k_en and k_de
    }
  }
  __syncthreads();

  // softmax + write: wave 0, one row per lane. KERN layout: [site][o][q].
  if (tid < 64) {
    int sbase = tid * 27;
#define SLD_(i) float s##i = score[sbase + (i)];
    REP25(SLD_)
    float mx = s0;
#define SMX_(i) mx = fmaxf(mx, s##i);
    REP25(SMX_)
    float sum = 0.f;
#define SEX_(i) s##i = __expf(s##i - mx); sum += s##i;
    REP25(SEX_)
    float inv = 1.f / sum;
    int cl = tid >> 2, qq = tid & 3;
    int hh = th0 + (cl >> 2), ww2 = tw0 + (cl & 3);
    float* kp = KERN + (size_t)(b * 6400 + hh * 80 + ww2) * 100;
#define SWR_(i) kp[(i) * 4 + qq] = s##i * inv;
    REP25(SWR_)
  }
}

// ---------------------------------------------------------------------------
// final: CARAFE + gate blend. Grid = B x 200 tiles x 8 channel-chunks.
// Block = 256 threads = 32 cells (8w x 4h) x 8 sub-groups of 4 channels.
// KERN is [site][o][q] -> 25 named float4 regs (q = .x/.y/.z/.w = (s1 s2)).
// ---------------------------------------------------------------------------
__global__ __launch_bounds__(256) void fade_final(
    const float* __restrict__ en, const float* __restrict__ de,
    const float* __restrict__ KERN, const float* __restrict__ GATE,
    float* __restrict__ out) {
  __shared__ float sde[32 * 105];   // 32 channels x (8 rows x 13 cols pad)
  int bi = blockIdx.x;
  int b = bi / 1600, r = bi % 1600;
  int t = r >> 3, cc = r & 7;
  int th0 = (t / 10) * 4, tw0 = (t % 10) * 8;
  int tid = threadIdx.x;
  int sg = tid >> 5, cell = tid & 31;
  int chh = cell >> 3, cw = cell & 7;
  int h = th0 + chh, w = tw0 + cw;

  // stage de: channels cc*32 .. +32, rows th0-2..+5, cols tw0-2..+9
  for (int kk = tid; kk < 3072; kk += 256) {
    int ci = kk / 96, rem = kk % 96, rr = rem / 12, c2 = rem % 12;
    int dr = th0 - 2 + rr, dc = tw0 - 2 + c2;
    float v = 0.f;
    if (dr >= 0 && dr < HH && dc >= 0 && dc < WW)
      v = de[((size_t)(b * CHN + cc * 32 + ci) * HH + dr) * WW + dc];
    sde[ci * 105 + rr * 13 + c2] = v;
  }
  __syncthreads();

  const float4* kp4 = (const float4*)(KERN + (size_t)(b * 6400 + h * 80 + w) * 100);
#define FKD_(i) float4 k##i = kp4[(i)];
  REP25(FKD_)
  float gv = GATE[((size_t)b * 80 + h) * 80 + w];
  float gv1 = 1.f - gv;

#pragma unroll
  for (int j = 0; j < 4; ++j) {
    int c = cc * 32 + sg * 4 + j;
    int sbase2 = (sg * 4 + j) * 105 + chh * 13 + cw;
#define FWD_(i) float w##i = sde[sbase2 + ((i) / 5) * 13 + ((i) % 5)];
    REP25(FWD_)
    float s00 = 0.f, s01 = 0.f, s10 = 0.f, s11 = 0.f;
#define FCF_(i) s00 = fmaf(w##i, k##i.x, s00); s01 = fmaf(w##i, k##i.y, s01); \
                s10 = fmaf(w##i, k##i.z, s10); s11 = fmaf(w##i, k##i.w, s11);
    REP25(FCF_)

    const float* ep = en + ((size_t)(b * CHN + c) * HO + 2 * h) * WO + 2 * w;
    float* op = out + ((size_t)(b * CHN + c) * HO + 2 * h) * WO + 2 * w;
    float2 e0 = *(const float2*)(ep);
    float2 e1 = *(const float2*)(ep + WO);
    float2 r0, r1;
    r0.x = fmaf(gv, e0.x, gv1 * s00);
    r0.y = fmaf(gv, e0.y, gv1 * s01);
    r1.x = fmaf(gv, e1.x, gv1 * s10);
    r1.y = fmaf(gv, e1.y, gv1 * s11);
    *(float2*)(op) = r0;
    *(float2*)(op + WO) = r1;
  }
}

// ---------------------------------------------------------------------------
extern "C" void kernel_launch(void* const* d_in, const int* in_sizes, int n_in,
                              void* d_out, int out_size, void* d_ws, size_t ws_size,
                              hipStream_t stream) {
  const float* en      = (const float*)d_in[0];
  const float* de      = (const float*)d_in[1];
  const float* gate_w  = (const float*)d_in[2];
  const float* gate_b  = (const float*)d_in[3];
  const float* w1_en   = (const float*)d_in[4];
  const float* b1_en   = (const float*)d_in[5];
  const float* w1_de   = (const float*)d_in[6];
  const float* conv2_k = (const float*)d_in[7];
  const float* conv2_b = (const float*)d_in[8];
  float* ws  = (float*)d_ws;
  float* out = (float*)d_out;

  float* wt_en = ws + OFF_WT_EN;
  float* wt_de = ws + OFF_WT_DE;
  float* wc    = ws + OFF_WC;
  float* cesb  = ws + OFF_CES;
  float* cdgb  = ws + OFF_CDG;
  float* gateo = ws + OFF_GATE;
  float* kernb = ws + OFF_KERN;

  hipLaunchKernelGGL(fade_prep,   dim3(64),   dim3(256), 0, stream, w1_en, w1_de, conv2_k, ws);
  hipLaunchKernelGGL(fade_border, dim3(322),  dim3(256), 0, stream, cesb);
  hipLaunchKernelGGL(fade_conv1a, dim3(960),  dim3(512), 0, stream, en, b1_en, wt_en, cesb);
  hipLaunchKernelGGL(fade_conv1b, dim3(211),  dim3(256), 0, stream,
                     de, gate_w, gate_b, wt_de, cdgb, gateo);
  hipLaunchKernelGGL(fade_kern,   dim3(800),  dim3(512), 0, stream,
                     wc, cesb, cdgb, conv2_b, kernb);
  hipLaunchKernelGGL(fade_final,  dim3(3200), dim3(256), 0, stream,
                     en, de, kernb, gateo, out);
}

// Round 14
// 136.772 us; speedup vs baseline: 1.2594x; 1.1708x over previous
//
#include <hip/hip_runtime.h>
#include <hip/hip_bf16.h>

// Problem constants
constexpr int BB  = 2;
constexpr int CHN = 256;
constexpr int HH  = 80;
constexpr int WW  = 80;
constexpr int EE  = 64;
constexpr int HO  = 160;
constexpr int WO  = 160;

// Workspace layout (float offsets)
constexpr int OFF_WT_EN = 0;                    // now: BF bf16 B-fragments (16384 ushort = 8192 floats)
constexpr int OFF_WT_DE = 16384;                // [256][64]  w1_de transposed
constexpr int OFF_WC    = 32768;                // [64][3][3][25] conv2_k transposed
constexpr int OFF_CES   = 47168;                // [B][4][162][162][16] padded+scrambled ce
constexpr int CES_SZ    = 2 * 4 * 162 * 162 * 16;   // 3,359,232
constexpr int OFF_CDG   = OFF_CES + CES_SZ;     // [B][82][82][64] padded cd
constexpr int CDG_SZ    = 2 * 82 * 82 * 64;     // 860,672
constexpr int OFF_GATE  = OFF_CDG + CDG_SZ;     // [B][80][80]
constexpr int OFF_KERN  = OFF_GATE + 2 * 80 * 80;   // [B][80][80][25][4] softmaxed (o-major, q-minor!)

constexpr int NPB = BB * 82 * 82;     // 13448

using bf16x8 = __attribute__((ext_vector_type(8))) short;
using f32x4  = __attribute__((ext_vector_type(4))) float;

// X-macro: apply F to 0..24 (forces compile-time indices -> registers; rule #20)
#define REP25(F) F(0) F(1) F(2) F(3) F(4) F(5) F(6) F(7) F(8) F(9) F(10) F(11) \
                 F(12) F(13) F(14) F(15) F(16) F(17) F(18) F(19) F(20) F(21) F(22) F(23) F(24)

// ---------------------------------------------------------------------------
// Prep: wt_de transpose (conv1b), WC transpose (kern), and BF = bf16 MFMA
// B-fragments of w1_en for conv1a:
//   BF[((ks*4+et)*64 + l)*8 + j] = bf16(w1_en[e][c]),
//   e = et*16 + (l&15), c = ks*32 + (l>>4)*8 + j
// ---------------------------------------------------------------------------
__global__ __launch_bounds__(256) void fade_prep(
    const float* __restrict__ w1_en, const float* __restrict__ w1_de,
    const float* __restrict__ conv2_k, float* __restrict__ ws) {
  int idx = blockIdx.x * 256 + threadIdx.x;
  if (idx < 16384) {
    int c = idx >> 6, e = idx & 63;           // dest = [c][e]
    ws[OFF_WT_DE + idx] = w1_de[e * CHN + c];
    // BF fragment (reuses old wt_en slot, as ushort)
    int j = idx & 7, l = (idx >> 3) & 63, et = (idx >> 9) & 3, ks = idx >> 11;
    int cc = ks * 32 + (l >> 4) * 8 + j;
    int ee = et * 16 + (l & 15);
    unsigned u = __float_as_uint(w1_en[ee * CHN + cc]);
    u = (u + 0x7FFFu + ((u >> 16) & 1u)) >> 16;   // RNE to bf16
    ((unsigned short*)(ws + OFF_WT_EN))[idx] = (unsigned short)u;
  }
  if (idx < 14400) {
    // dest idx = (e*9 + t)*25 + o ; src = conv2_k[(o*64 + e)*9 + t]
    int e = idx / 225, rem = idx % 225, t = rem / 25, o = rem % 25;
    ws[OFF_WC + idx] = conv2_k[(o * EE + e) * 9 + t];
  }
}

// ---------------------------------------------------------------------------
// border: zero-fill the pad border of ce_s (yy=0,161; xx=0,161).
// ---------------------------------------------------------------------------
__global__ __launch_bounds__(256) void fade_border(float* __restrict__ ces) {
  int idx = blockIdx.x * 256 + threadIdx.x;
  if (idx >= 82432) return;
  int e4 = idx & 3;
  int rest = idx >> 2;
  int posb = rest % 644;
  int rest2 = rest / 644;
  int q = rest2 & 3, b = rest2 >> 2;
  int yy, xx;
  if (posb < 162)      { yy = 0;   xx = posb; }
  else if (posb < 324) { yy = 161; xx = posb - 162; }
  else if (posb < 484) { xx = 0;   yy = posb - 324 + 1; }
  else                 { xx = 161; yy = posb - 484 + 1; }
  float4 z = make_float4(0.f, 0.f, 0.f, 0.f);
  *(float4*)(ces + ((((size_t)b * 4 + q) * 162 + yy) * 162 + xx) * 16 + e4 * 4) = z;
}

// ---------------------------------------------------------------------------
// conv1a: ce = 1x1(en) via bf16 MFMA (r13: fp32 VALU path stuck at 30% busy,
// floor ~20us; matrix pipe makes compute free -> staging-bound ~15us).
// GEMM M=25600/batch, N=64, K=256. Block = 256 thr = 4 waves = 64 pos;
// wave = 16 pos x 64 e = 4 mfma_f32_16x16x32_bf16 per K-step, 8 K-steps.
// A: en staged fp32 in LDS [32][65] (2-way bank alias only), cvt->bf16 RNE.
// B: precomputed bf16 frags (L2-hot, 2KB). Bias via fp32 C-in.
// Lane maps: A row=l&15,kblk=l>>4; B col=l&15,kblk=l>>4; D col=l&15,
// row=(l>>4)*4+r (guide-verified). k-permutation cancels between A and B.
// ---------------------------------------------------------------------------
__global__ __launch_bounds__(256) void fade_conv1a(
    const float* __restrict__ en, const float* __restrict__ b1_en,
    const unsigned short* __restrict__ BFu, float* __restrict__ ces) {
  __shared__ float buf[32][65];
  int bi = blockIdx.x;
  int b = bi / 400;
  int pos0 = (bi % 400) * 64;       // within batch plane (25600)
  int tid = threadIdx.x;
  int lane = tid & 63;
  int w = __builtin_amdgcn_readfirstlane(tid >> 6);   // 0..3
  int l15 = lane & 15, lg = lane >> 4;

  const float* ep = en + (size_t)b * CHN * 25600 + pos0;
  const bf16x8* BFF = (const bf16x8*)BFu;

  f32x4 acc0, acc1, acc2, acc3;
  { float bv = b1_en[l15];      acc0 = (f32x4){bv, bv, bv, bv}; }
  { float bv = b1_en[16 + l15]; acc1 = (f32x4){bv, bv, bv, bv}; }
  { float bv = b1_en[32 + l15]; acc2 = (f32x4){bv, bv, bv, bv}; }
  { float bv = b1_en[48 + l15]; acc3 = (f32x4){bv, bv, bv, bv}; }

  int cg = tid >> 6, po = tid & 63;
  for (int ks = 0; ks < 8; ++ks) {
    __syncthreads();
#pragma unroll
    for (int i = 0; i < 8; ++i) {
      int c = i * 4 + cg;
      buf[c][po] = ep[(size_t)(ks * 32 + c) * 25600 + po];
    }
    __syncthreads();
    bf16x8 av;
#define LDA_(j) { unsigned u = __float_as_uint(buf[lg * 8 + (j)][w * 16 + l15]); \
    u = (u + 0x7FFFu + ((u >> 16) & 1u)) >> 16; av[(j)] = (short)u; }
    LDA_(0) LDA_(1) LDA_(2) LDA_(3) LDA_(4) LDA_(5) LDA_(6) LDA_(7)
#undef LDA_
    const bf16x8* bp = BFF + ks * 256 + lane;
    bf16x8 b0 = bp[0], b1 = bp[64], b2 = bp[128], b3 = bp[192];
    acc0 = __builtin_amdgcn_mfma_f32_16x16x32_bf16(av, b0, acc0, 0, 0, 0);
    acc1 = __builtin_amdgcn_mfma_f32_16x16x32_bf16(av, b1, acc1, 0, 0, 0);
    acc2 = __builtin_amdgcn_mfma_f32_16x16x32_bf16(av, b2, acc2, 0, 0, 0);
    acc3 = __builtin_amdgcn_mfma_f32_16x16x32_bf16(av, b3, acc3, 0, 0, 0);
  }

  // scrambled write: ce_s[b][q][yy][xx][e'] = acc_full[4e'+q]; e = 4e'+q
  constexpr size_t QSTR = (size_t)162 * 162 * 16;
  float* cb = ces + (size_t)b * 4 * QSTR;
  int pbase = pos0 + w * 16 + lg * 4;
  int q = l15 & 3;
#define WR_(r) { int p = pbase + (r); int y = p / 160, x = p - y * 160; \
    size_t sb = (size_t)q * QSTR + (size_t)((y + 1) * 162 + (x + 1)) * 16 + (l15 >> 2); \
    cb[sb +  0] = acc0[(r)]; \
    cb[sb +  4] = acc1[(r)]; \
    cb[sb +  8] = acc2[(r)]; \
    cb[sb + 12] = acc3[(r)]; }
  WR_(0) WR_(1) WR_(2) WR_(3)
#undef WR_
}

// ---------------------------------------------------------------------------
// conv1b: cd = 1x1(de) -> padded cdg, + gate. Exact r7 part-B shape
// (256 thr, 4 e-groups x acc[16]) -- measured healthy at r7.
// ---------------------------------------------------------------------------
__global__ __launch_bounds__(256) void fade_conv1b(
    const float* __restrict__ de,
    const float* __restrict__ gate_w, const float* __restrict__ gate_b,
    const float* __restrict__ wt_de,
    float* __restrict__ cdg, float* __restrict__ gateo) {
  int tid = threadIdx.x;
  int id64 = tid & 63;
  int eg = __builtin_amdgcn_readfirstlane(tid >> 6);   // 0..3
  int pos = blockIdx.x * 64 + id64;
  if (pos >= NPB) return;

  int b = pos / (82 * 82), r = pos % (82 * 82);
  int yy = r / 82, xx = r % 82;
  int y = yy - 1, x = xx - 1;
  float* cop = cdg + (((size_t)b * 82 + yy) * 82 + xx) * 64 + eg * 16;
  if (y >= 0 && y < HH && x >= 0 && x < WW) {
    float acc[16];
#pragma unroll
    for (int e = 0; e < 16; ++e) acc[e] = 0.f;
    float g = gate_b[0];
    const float* dp = de + (size_t)b * CHN * HH * WW + (size_t)y * WW + x;
    float cur[8];
#pragma unroll
    for (int j = 0; j < 8; ++j) cur[j] = dp[(size_t)j * HH * WW];
    for (int c0 = 0; c0 < CHN; c0 += 8) {
      float nxt[8];
      if (c0 + 8 < CHN) {
#pragma unroll
        for (int j = 0; j < 8; ++j) nxt[j] = dp[(size_t)(c0 + 8 + j) * HH * WW];
      }
#pragma unroll
      for (int j = 0; j < 8; ++j) {
        float v = cur[j];
        const float* wr = wt_de + (c0 + j) * 64 + eg * 16;
#pragma unroll
        for (int e = 0; e < 16; ++e) acc[e] = fmaf(v, wr[e], acc[e]);
        g = fmaf(v, gate_w[c0 + j], g);
      }
      if (c0 + 8 < CHN) {
#pragma unroll
        for (int j = 0; j < 8; ++j) cur[j] = nxt[j];
      }
    }
#pragma unroll
    for (int m = 0; m < 4; ++m) {
      float4 v = make_float4(acc[4 * m], acc[4 * m + 1], acc[4 * m + 2], acc[4 * m + 3]);
      *(float4*)(cop + m * 4) = v;
    }
    if (eg == 0)
      gateo[((size_t)b * 80 + y) * 80 + x] = 1.f / (1.f + __expf(-g));
  } else {
    float4 z = make_float4(0.f, 0.f, 0.f, 0.f);
#pragma unroll
    for (int m = 0; m < 4; ++m) *(float4*)(cop + m * 4) = z;
  }
}

// ---------------------------------------------------------------------------
// kern: MERGED k_de+k_en tap loop (r13: sum activations first, half FMAs).
// Runtime d-loop retained (r8 lesson); two-phase LDS reduction (32KB).
// ---------------------------------------------------------------------------
__global__ __launch_bounds__(512) void fade_kern(
    const float* __restrict__ WC, const float* __restrict__ CES,
    const float* __restrict__ CDG, const float* __restrict__ conv2_b,
    float* __restrict__ KERN) {
  __shared__ float part[64 * 101];   // [row][(wv&3)*25+o], stride 101 (conflict-free)
  __shared__ float score[64 * 27];
  int bi = blockIdx.x;
  int b = bi / 400, t = bi % 400;
  int th0 = (t / 20) * 4, tw0 = (t % 20) * 4;
  int tid = threadIdx.x;
  int lane = tid & 63;
  int wv = __builtin_amdgcn_readfirstlane(tid >> 6);   // 0..7 K-slice
  int cell = lane >> 2, q = lane & 3;
  int h = th0 + (cell >> 2), w = tw0 + (cell & 3);

#define KDECL_(i) float a##i = 0.f;
  REP25(KDECL_)

#define KCH(val, base) { const float vv = (val); const float* wb = (base); \
    REP25(KFMA_) }
#define KFMA_(i) a##i = fmaf(vv, wb[(i)], a##i);

  // merged k_de + k_en over 9 taps; channels 8wv..8wv+8
  {
    int g = wv >> 1;
    const int pt = (g < 2) ? 1 : 0;
    const int pl = (g & 1) ? 0 : 1;
    const int eb = 8 * (wv & 1);
    for (int d = 0; d < 9; ++d) {
      int di = d / 3, dj = d - 3 * di;
      const float* cpd = CDG + (((size_t)b * 82 + (h + di)) * 82 + (w + dj)) * 64 + 8 * wv;
      float4 u0 = *(const float4*)(cpd);
      float4 u1 = *(const float4*)(cpd + 4);
      int yy = 2 * h + di - pt + 1;
      int xx = 2 * w + dj - pl + 1;
      const float* cpe = CES + ((((size_t)b * 4 + q) * 162 + yy) * 162 + xx) * 16 + eb;
      float4 v0 = *(const float4*)(cpe);
      float4 v1 = *(const float4*)(cpe + 4);
      const float* wt = WC + (8 * wv * 9 + d) * 25;
      KCH(u0.x + v0.x, wt)         KCH(u0.y + v0.y, wt + 225)
      KCH(u0.z + v0.z, wt + 450)   KCH(u0.w + v0.w, wt + 675)
      KCH(u1.x + v1.x, wt + 900)   KCH(u1.y + v1.y, wt + 1125)
      KCH(u1.z + v1.z, wt + 1350)  KCH(u1.w + v1.w, wt + 1575)
    }
  }

  {
    int pbase = lane * 101 + (wv & 3) * 25;
    if (wv < 4) {
#define KST_(i) part[pbase + (i)] = a##i;
      REP25(KST_)
    }
    __syncthreads();
    if (wv >= 4) {
#define KAD_(i) part[pbase + (i)] += a##i;
      REP25(KAD_)
    }
  }
  __syncthreads();

  {
    int row = tid & 63, sub = tid >> 6;
    int nO = (sub == 7) ? 4 : 3;
    for (int m = 0; m < nO; ++m) {
      int o = sub * 3 + m;
      float s = 0.f;
#pragma unroll
      for (int w4 = 0; w4 < 4; ++w4) s += part[row * 101 + w4 * 25 + o];
      score[row * 27 + o] = s + 2.f * conv2_b[o];   // bias in BOTH k_en and k_de
    }
  }
  __syncthreads();

  if (tid < 64) {
    int sbase = tid * 27;
#define SLD_(i) float s##i = score[sbase + (i)];
    REP25(SLD_)
    float mx = s0;
#define SMX_(i) mx = fmaxf(mx, s##i);
    REP25(SMX_)
    float sum = 0.f;
#define SEX_(i) s##i = __expf(s##i - mx); sum += s##i;
    REP25(SEX_)
    float inv = 1.f / sum;
    int cl = tid >> 2, qq = tid & 3;
    int hh = th0 + (cl >> 2), ww2 = tw0 + (cl & 3);
    float* kp = KERN + (size_t)(b * 6400 + hh * 80 + ww2) * 100;
#define SWR_(i) kp[(i) * 4 + qq] = s##i * inv;
    REP25(SWR_)
  }
}

// ---------------------------------------------------------------------------
// final: CARAFE + gate blend. Grid = B x 200 tiles x 8 channel-chunks.
// ---------------------------------------------------------------------------
__global__ __launch_bounds__(256) void fade_final(
    const float* __restrict__ en, const float* __restrict__ de,
    const float* __restrict__ KERN, const float* __restrict__ GATE,
    float* __restrict__ out) {
  __shared__ float sde[32 * 105];   // 32 channels x (8 rows x 13 cols pad)
  int bi = blockIdx.x;
  int b = bi / 1600, r = bi % 1600;
  int t = r >> 3, cc = r & 7;
  int th0 = (t / 10) * 4, tw0 = (t % 10) * 8;
  int tid = threadIdx.x;
  int sg = tid >> 5, cell = tid & 31;
  int chh = cell >> 3, cw = cell & 7;
  int h = th0 + chh, w = tw0 + cw;

  for (int kk = tid; kk < 3072; kk += 256) {
    int ci = kk / 96, rem = kk % 96, rr = rem / 12, c2 = rem % 12;
    int dr = th0 - 2 + rr, dc = tw0 - 2 + c2;
    float v = 0.f;
    if (dr >= 0 && dr < HH && dc >= 0 && dc < WW)
      v = de[((size_t)(b * CHN + cc * 32 + ci) * HH + dr) * WW + dc];
    sde[ci * 105 + rr * 13 + c2] = v;
  }
  __syncthreads();

  const float4* kp4 = (const float4*)(KERN + (size_t)(b * 6400 + h * 80 + w) * 100);
#define FKD_(i) float4 k##i = kp4[(i)];
  REP25(FKD_)
  float gv = GATE[((size_t)b * 80 + h) * 80 + w];
  float gv1 = 1.f - gv;

#pragma unroll
  for (int j = 0; j < 4; ++j) {
    int c = cc * 32 + sg * 4 + j;
    int sbase2 = (sg * 4 + j) * 105 + chh * 13 + cw;
#define FWD_(i) float w##i = sde[sbase2 + ((i) / 5) * 13 + ((i) % 5)];
    REP25(FWD_)
    float s00 = 0.f, s01 = 0.f, s10 = 0.f, s11 = 0.f;
#define FCF_(i) s00 = fmaf(w##i, k##i.x, s00); s01 = fmaf(w##i, k##i.y, s01); \
                s10 = fmaf(w##i, k##i.z, s10); s11 = fmaf(w##i, k##i.w, s11);
    REP25(FCF_)

    const float* ep = en + ((size_t)(b * CHN + c) * HO + 2 * h) * WO + 2 * w;
    float* op = out + ((size_t)(b * CHN + c) * HO + 2 * h) * WO + 2 * w;
    float2 e0 = *(const float2*)(ep);
    float2 e1 = *(const float2*)(ep + WO);
    float2 r0, r1;
    r0.x = fmaf(gv, e0.x, gv1 * s00);
    r0.y = fmaf(gv, e0.y, gv1 * s01);
    r1.x = fmaf(gv, e1.x, gv1 * s10);
    r1.y = fmaf(gv, e1.y, gv1 * s11);
    *(float2*)(op) = r0;
    *(float2*)(op + WO) = r1;
  }
}

// ---------------------------------------------------------------------------
extern "C" void kernel_launch(void* const* d_in, const int* in_sizes, int n_in,
                              void* d_out, int out_size, void* d_ws, size_t ws_size,
                              hipStream_t stream) {
  const float* en      = (const float*)d_in[0];
  const float* de      = (const float*)d_in[1];
  const float* gate_w  = (const float*)d_in[2];
  const float* gate_b  = (const float*)d_in[3];
  const float* w1_en   = (const float*)d_in[4];
  const float* b1_en   = (const float*)d_in[5];
  const float* w1_de   = (const float*)d_in[6];
  const float* conv2_k = (const float*)d_in[7];
  const float* conv2_b = (const float*)d_in[8];
  float* ws  = (float*)d_ws;
  float* out = (float*)d_out;

  const unsigned short* bfu = (const unsigned short*)(ws + OFF_WT_EN);
  float* wt_de = ws + OFF_WT_DE;
  float* wc    = ws + OFF_WC;
  float* cesb  = ws + OFF_CES;
  float* cdgb  = ws + OFF_CDG;
  float* gateo = ws + OFF_GATE;
  float* kernb = ws + OFF_KERN;

  hipLaunchKernelGGL(fade_prep,   dim3(64),   dim3(256), 0, stream, w1_en, w1_de, conv2_k, ws);
  hipLaunchKernelGGL(fade_border, dim3(322),  dim3(256), 0, stream, cesb);
  hipLaunchKernelGGL(fade_conv1a, dim3(800),  dim3(256), 0, stream, en, b1_en, bfu, cesb);
  hipLaunchKernelGGL(fade_conv1b, dim3(211),  dim3(256), 0, stream,
                     de, gate_w, gate_b, wt_de, cdgb, gateo);
  hipLaunchKernelGGL(fade_kern,   dim3(800),  dim3(512), 0, stream,
                     wc, cesb, cdgb, conv2_b, kernb);
  hipLaunchKernelGGL(fade_final,  dim3(3200), dim3(256), 0, stream,
                     en, de, kernb, gateo, out);
}